// Round 7
// baseline (376.825 us; speedup 1.0000x reference)
//
#include <hip/hip_runtime.h>
#include <cmath>

#define NB 8
#define NPTS 2048
#define NE (NB * NPTS)
#define THREADS 512
#define RPW 8      // rows per wave; wave-pairs split the j-range in half

#if defined(__has_builtin)
#if __has_builtin(__builtin_amdgcn_exp2f)
#define FAST_EXP2(x) __builtin_amdgcn_exp2f(x)
#else
#define FAST_EXP2(x) exp2f(x)
#endif
#if __has_builtin(__builtin_amdgcn_logf)
#define FAST_LOG2(x) __builtin_amdgcn_logf(x)
#else
#define FAST_LOG2(x) log2f(x)
#endif
#else
#define FAST_EXP2(x) exp2f(x)
#define FAST_LOG2(x) log2f(x)
#endif

// ---- DPP wave64 reductions (VALU pipe only; result valid at lane 63) ----
template<int CTRL>
__device__ __forceinline__ float dpp_f(float v) {
    return __int_as_float(__builtin_amdgcn_update_dpp(
        __float_as_int(v), __float_as_int(v), CTRL, 0xF, 0xF, false));
}
__device__ __forceinline__ float wred_max(float v) {
    v = fmaxf(v, dpp_f<0xB1>(v));
    v = fmaxf(v, dpp_f<0x4E>(v));
    v = fmaxf(v, dpp_f<0x141>(v));
    v = fmaxf(v, dpp_f<0x140>(v));
    v = fmaxf(v, dpp_f<0x142>(v));
    v = fmaxf(v, dpp_f<0x143>(v));
    return v;  // lane 63 correct
}
__device__ __forceinline__ float wred_sum(float v) {
    v += dpp_f<0xB1>(v);
    v += dpp_f<0x4E>(v);
    v += dpp_f<0x141>(v);
    v += dpp_f<0x140>(v);
    v += dpp_f<0x142>(v);
    v += dpp_f<0x143>(v);
    return v;  // lane 63 correct
}

// One Sinkhorn "phase": softmin_eps(C,h) for all rows of both sides, damped.
// Wave-pair structure: waves 2k,2k+1 share 8 rows; each sums half the 2048
// j's (16 ds_read_b128/wave), partials combined through LDS. Stabilizer
// m_est = prev phase's LSE scaled by eps ratio; band-validated (s in
// (1e-30,1e34) => full fp32 precision), block-uniform exact redo otherwise.
__global__ __launch_bounds__(THREADS, 8) void sinkhorn_phase(
    const float* __restrict__ x, const float* __restrict__ y,
    const float* __restrict__ loga, const float* __restrict__ logb,
    const float* __restrict__ f_prev, const float* __restrict__ g_prev,
    float* __restrict__ f_next, float* __restrict__ g_next,
    float* __restrict__ Ls,          // [2][NB][NPTS] log2-domain LSE store
    float eps, float inv_eps, float c_old, float c_new,
    float mscale, int initPhase)
{
    __shared__ float4 tile[NPTS];   // {y.x, y.y, hc(log2), pad}
    __shared__ float xch[8][RPW];   // wave-pair partial exchange

    const int blk = blockIdx.x;
    const int side = blk >> 9;          // 512 blocks/side
    const int rblk = blk & 511;
    const int batch = rblk >> 6;        // 64 row-tiles (32 rows) per batch
    const int rowTile = rblk & 63;

    const float* rowPts; const float* colPts; const float* hlog;
    const float* hpot; const float* ownPrev; float* outPot;
    if (side == 0) { rowPts=x; colPts=y; hlog=logb; hpot=g_prev; ownPrev=f_prev; outPot=f_next; }
    else           { rowPts=y; colPts=x; hlog=loga; hpot=f_prev; ownPrev=g_prev; outPot=g_next; }

    const float LOG2E = 1.4426950408889634f;
    const float LN2 = 0.69314718055994531f;

    // Stage columns + log2-domain column constant into LDS (4 iters).
    const float2* cp2 = (const float2*)(colPts + (size_t)batch*NPTS*2);
    const float* hl = hlog + (size_t)batch*NPTS;
    const float* pp = hpot + (size_t)batch*NPTS;
    for (int j = threadIdx.x; j < NPTS; j += THREADS) {
        float2 p = cp2[j];
        float hp = initPhase ? 0.0f : pp[j] * inv_eps;
        float hcv = (hl[j] + hp - 0.5f*inv_eps*fmaf(p.x, p.x, p.y*p.y)) * LOG2E;
        tile[j] = make_float4(p.x, p.y, hcv, 0.0f);
    }
    __syncthreads();

    const int lane = threadIdx.x & 63;
    const int wv = threadIdx.x >> 6;        // 8 waves/block
    const int pairId = wv >> 1;             // 4 pairs x 8 rows = 32 rows/block
    const int half = wv & 1;                // which j-half this wave sums
    const int row0 = rowTile*32 + pairId*RPW;
    const int gidx0 = batch*NPTS + row0;
    const float2* rp2 = (const float2*)(rowPts + (size_t)batch*NPTS*2) + row0;
    const float* Lp = Ls + side*NE + gidx0;

    const float sc = inv_eps * LOG2E;
    float rx[RPW], ry[RPW], mest[RPW], s[RPW];
    #pragma unroll
    for (int r = 0; r < RPW; r++) {
        float2 p = rp2[r];
        rx[r] = p.x * sc;
        ry[r] = p.y * sc;
        mest[r] = initPhase ? 0.0f : Lp[r] * mscale;
        s[r] = 0.0f;
    }

    const int jbase = (half << 10) + lane;  // this wave's 1024-j half

    // Fused pass over own half: 2 fma + 1 sub + 1 exp2 + 1 add per element.
    #pragma unroll 4
    for (int it = 0; it < 16; it++) {
        float4 t4 = tile[jbase + (it << 6)];
        #pragma unroll
        for (int r = 0; r < RPW; r++) {
            float t = fmaf(rx[r], t4.x, fmaf(ry[r], t4.y, t4.z)) - mest[r];
            s[r] += FAST_EXP2(t);
        }
    }
    #pragma unroll
    for (int r = 0; r < RPW; r++) s[r] = wred_sum(s[r]);

    if (lane == 63) {
        #pragma unroll
        for (int r = 0; r < RPW; r++) xch[wv][r] = s[r];
    }
    __syncthreads();

    float stot[RPW];
    int bad = 0;
    #pragma unroll
    for (int r = 0; r < RPW; r++) {
        stot[r] = s[r] + xch[wv ^ 1][r];    // valid at lane 63
        if (lane == 63) bad |= !(stot[r] > 1e-30f && stot[r] < 1e34f);
    }

    // Block-uniform redo decision (keeps barriers legal).
    if (__syncthreads_or(bad)) {
        // Exact 2-pass redo over own half with pair-combined max.
        float mm[RPW];
        #pragma unroll
        for (int r = 0; r < RPW; r++) mm[r] = -3.4e38f;
        #pragma unroll 4
        for (int it = 0; it < 16; it++) {
            float4 t4 = tile[jbase + (it << 6)];
            #pragma unroll
            for (int r = 0; r < RPW; r++) {
                float t = fmaf(rx[r], t4.x, fmaf(ry[r], t4.y, t4.z)) - mest[r];
                mm[r] = fmaxf(mm[r], t);
            }
        }
        #pragma unroll
        for (int r = 0; r < RPW; r++) mm[r] = wred_max(mm[r]);
        if (lane == 63) {
            #pragma unroll
            for (int r = 0; r < RPW; r++) xch[wv][r] = mm[r];
        }
        __syncthreads();
        float mmc[RPW];
        #pragma unroll
        for (int r = 0; r < RPW; r++) {
            mmc[r] = fmaxf(xch[wv][r], xch[wv ^ 1][r]);  // uniform in pair
            s[r] = 0.0f;
        }
        __syncthreads();   // xch reusable after everyone read it
        #pragma unroll 4
        for (int it = 0; it < 16; it++) {
            float4 t4 = tile[jbase + (it << 6)];
            #pragma unroll
            for (int r = 0; r < RPW; r++) {
                float t = fmaf(rx[r], t4.x, fmaf(ry[r], t4.y, t4.z)) - mest[r];
                s[r] += FAST_EXP2(t - mmc[r]);
            }
        }
        #pragma unroll
        for (int r = 0; r < RPW; r++) s[r] = wred_sum(s[r]);
        if (lane == 63) {
            #pragma unroll
            for (int r = 0; r < RPW; r++) xch[wv][r] = s[r];
        }
        __syncthreads();
        #pragma unroll
        for (int r = 0; r < RPW; r++) {
            stot[r] = s[r] + xch[wv ^ 1][r];
            mest[r] += mmc[r];              // final L = mest + mmc + log2(stot)
        }
    }

    // Epilogue: even wave of each pair, lane 63 writes the 8 rows.
    if (lane == 63 && half == 0) {
        #pragma unroll
        for (int r = 0; r < RPW; r++) {
            float2 p = rp2[r];
            float hr = -0.5f * sc * fmaf(p.x, p.x, p.y * p.y);
            float L = mest[r] + FAST_LOG2(stot[r]);       // log2-domain LSE
            float sm = -eps * LN2 * (hr + L);             // softmin value
            outPot[gidx0 + r] = c_old * ownPrev[gidx0 + r] + c_new * sm;
            Ls[side*NE + gidx0 + r] = L;                  // estimator for next phase
        }
    }
}

__global__ void log_precompute(const float* __restrict__ a, const float* __restrict__ b,
                               float* __restrict__ loga, float* __restrict__ logb, int n)
{
    int i = blockIdx.x * blockDim.x + threadIdx.x;
    if (i < n) {
        loga[i] = logf(a[i]);
        logb[i] = logf(b[i]);
    }
}

__global__ __launch_bounds__(1024) void loss_reduce(
    const float* __restrict__ a, const float* __restrict__ bw,
    const float* __restrict__ f, const float* __restrict__ g,
    float* __restrict__ out)
{
    const float4* a4 = (const float4*)a;
    const float4* b4 = (const float4*)bw;
    const float4* f4 = (const float4*)f;
    const float4* g4 = (const float4*)g;
    float acc = 0.0f;
    for (int i = threadIdx.x; i < NE/4; i += 1024) {
        float4 av = a4[i], fv = f4[i], bv = b4[i], gv = g4[i];
        acc += av.x*fv.x + av.y*fv.y + av.z*fv.z + av.w*fv.w;
        acc += bv.x*gv.x + bv.y*gv.y + bv.z*gv.z + bv.w*gv.w;
    }
    acc += __shfl_xor(acc, 32);
    acc += __shfl_xor(acc, 16);
    acc += __shfl_xor(acc, 8);
    acc += __shfl_xor(acc, 4);
    acc += __shfl_xor(acc, 2);
    acc += __shfl_xor(acc, 1);
    __shared__ float wsum[16];
    int wid = threadIdx.x >> 6;
    if ((threadIdx.x & 63) == 0) wsum[wid] = acc;
    __syncthreads();
    if (threadIdx.x < 16) {
        float v = wsum[threadIdx.x];
        v += __shfl_xor(v, 8, 16);
        v += __shfl_xor(v, 4, 16);
        v += __shfl_xor(v, 2, 16);
        v += __shfl_xor(v, 1, 16);
        if (threadIdx.x == 0) out[0] = v * (1.0f / NB);
    }
}

extern "C" void kernel_launch(void* const* d_in, const int* in_sizes, int n_in,
                              void* d_out, int out_size, void* d_ws, size_t ws_size,
                              hipStream_t stream)
{
    const float* a = (const float*)d_in[0];
    const float* x = (const float*)d_in[1];
    const float* b = (const float*)d_in[2];
    const float* y = (const float*)d_in[3];
    float* out = (float*)d_out;

    float* ws = (float*)d_ws;
    float* loga = ws + 0 * NE;
    float* logb = ws + 1 * NE;
    float* fA   = ws + 2 * NE;
    float* gA   = ws + 3 * NE;
    float* fB   = ws + 4 * NE;
    float* gB   = ws + 5 * NE;
    float* Ls   = ws + 6 * NE;      // 2*NE floats

    // eps annealing schedule (host-side, as in reference)
    double eps_list[32];
    int ne = 0;
    const double eps_final = 0.05 * 0.05;   // blur^p
    double eps = 2.0 * 2.0;                  // diameter^p
    while (eps > eps_final) { eps_list[ne++] = eps; eps *= 0.64; }  // scaling^p
    eps_list[ne++] = eps_final;              // ne == 18

    log_precompute<<<(NE + 255) / 256, 256, 0, stream>>>(a, b, loga, logb, NE);

    const float* fp = fA; const float* gp = gA;
    float* fn = fB; float* gn = gB;

    auto phase = [&](double e, double e_prev, float c_old, float c_new, int init) {
        sinkhorn_phase<<<1024, THREADS, 0, stream>>>(
            x, y, loga, logb, fp, gp, fn, gn, Ls,
            (float)e, (float)(1.0 / e), c_old, c_new,
            (float)(e_prev / e), init);
    };
    auto swapbuf = [&]() {
        const float* tf = fp; const float* tg = gp;
        fp = fn; gp = gn;
        fn = (float*)tf; gn = (float*)tg;
    };

    // init at eps0: h = log_b only; un-stabilized exponents are O(1) so
    // mest = 0 is in-band (band check still guards).
    phase(eps_list[0], eps_list[0], 0.0f, 1.0f, 1);
    swapbuf();
    // annealed damped iterations
    double e_prev = eps_list[0];
    for (int k = 0; k < ne; k++) {
        phase(eps_list[k], e_prev, 0.5f, 0.5f, 0);
        e_prev = eps_list[k];
        swapbuf();
    }
    // final extrapolation at eps_final (no damping)
    phase(eps_list[ne - 1], e_prev, 0.0f, 1.0f, 0);
    // result potentials are in fn, gn

    loss_reduce<<<1, 1024, 0, stream>>>(a, b, fn, gn, out);
}

// Round 8
// 355.625 us; speedup vs baseline: 1.0596x; 1.0596x over previous
//
#include <hip/hip_runtime.h>
#include <cmath>

#define NB 8
#define NPTS 2048
#define NE (NB * NPTS)
#define THREADS 512
#define RPW 4   // rows per wave -> 32 rows/block, 1024 blocks

#if defined(__has_builtin)
#if __has_builtin(__builtin_amdgcn_exp2f)
#define FAST_EXP2(x) __builtin_amdgcn_exp2f(x)
#else
#define FAST_EXP2(x) exp2f(x)
#endif
#if __has_builtin(__builtin_amdgcn_logf)
#define FAST_LOG2(x) __builtin_amdgcn_logf(x)
#else
#define FAST_LOG2(x) log2f(x)
#endif
#else
#define FAST_EXP2(x) exp2f(x)
#define FAST_LOG2(x) log2f(x)
#endif

// ---- DPP wave64 reductions (VALU pipe only; result valid at lane 63) ----
template<int CTRL>
__device__ __forceinline__ float dpp_f(float v) {
    return __int_as_float(__builtin_amdgcn_update_dpp(
        __float_as_int(v), __float_as_int(v), CTRL, 0xF, 0xF, false));
}
__device__ __forceinline__ float wred_max(float v) {
    v = fmaxf(v, dpp_f<0xB1>(v));
    v = fmaxf(v, dpp_f<0x4E>(v));
    v = fmaxf(v, dpp_f<0x141>(v));
    v = fmaxf(v, dpp_f<0x140>(v));
    v = fmaxf(v, dpp_f<0x142>(v));
    v = fmaxf(v, dpp_f<0x143>(v));
    return v;  // lane 63 correct
}
__device__ __forceinline__ float wred_sum(float v) {
    v += dpp_f<0xB1>(v);
    v += dpp_f<0x4E>(v);
    v += dpp_f<0x141>(v);
    v += dpp_f<0x140>(v);
    v += dpp_f<0x142>(v);
    v += dpp_f<0x143>(v);
    return v;  // lane 63 correct
}

// One Sinkhorn "phase": softmin_eps(C,h) for all rows of both sides, damped.
// Packed LDS layout (12 B per column, LSE is j-order invariant):
//   xy4[k]  = {x_{2k}, y_{2k}, x_{2k+1}, y_{2k+1}}   (raw float4 copy)
//   hc4[it*64+l] = hc of cols {it*256+2l, +1, it*256+128+2l, +1} (permuted)
// Per wave-iter a lane reads 3x ds_read_b128 (all stride-16B, conflict-free)
// covering 4 full columns. Stabilizer m_est = prev LSE scaled by eps ratio;
// band-validated (s in (1e-30,1e34) => full fp32 precision), exact wave-local
// 2-pass redo otherwise.
__global__ __launch_bounds__(THREADS, 8) void sinkhorn_phase(
    const float* __restrict__ x, const float* __restrict__ y,
    const float* __restrict__ loga, const float* __restrict__ logb,
    const float* __restrict__ f_prev, const float* __restrict__ g_prev,
    float* __restrict__ f_next, float* __restrict__ g_next,
    float* __restrict__ Ls,          // [2][NB][NPTS] log2-domain LSE store
    float eps, float inv_eps, float c_old, float c_new,
    float mscale, int initPhase)
{
    __shared__ float4 xy4[NPTS / 2];   // 16 KB
    __shared__ float4 hc4[NPTS / 4];   // 8 KB

    const int blk = blockIdx.x;
    const int side = blk >> 9;          // 512 blocks/side
    const int rblk = blk & 511;
    const int batch = rblk >> 6;        // 64 row-tiles (32 rows) per batch
    const int rowTile = rblk & 63;

    const float* rowPts; const float* colPts; const float* hlog;
    const float* hpot; const float* ownPrev; float* outPot;
    if (side == 0) { rowPts=x; colPts=y; hlog=logb; hpot=g_prev; ownPrev=f_prev; outPot=f_next; }
    else           { rowPts=y; colPts=x; hlog=loga; hpot=f_prev; ownPrev=g_prev; outPot=g_next; }

    const float LOG2E = 1.4426950408889634f;
    const float LN2 = 0.69314718055994531f;

    // Stage xy: pure float4 copy of the column points.
    const float4* cp4 = ((const float4*)colPts) + (size_t)batch * (NPTS / 2);
    xy4[threadIdx.x]       = cp4[threadIdx.x];
    xy4[threadIdx.x + 512] = cp4[threadIdx.x + 512];

    // Stage hc, permuted to match the read pattern.
    {
        const float2* cp2 = (const float2*)(colPts + (size_t)batch * NPTS * 2);
        const float* hl = hlog + (size_t)batch * NPTS;
        const float* pp = hpot + (size_t)batch * NPTS;
        const int i = threadIdx.x;            // 512 entries, one per thread
        const int it = i >> 6, l = i & 63;
        const int j0 = it * 256 + 2 * l;
        const int j2 = j0 + 128;
        float2 pa = cp2[j0], pb = cp2[j0 + 1], pc = cp2[j2], pd = cp2[j2 + 1];
        float4 h;
        float hpa = initPhase ? 0.0f : pp[j0] * inv_eps;
        float hpb = initPhase ? 0.0f : pp[j0 + 1] * inv_eps;
        float hpc = initPhase ? 0.0f : pp[j2] * inv_eps;
        float hpd = initPhase ? 0.0f : pp[j2 + 1] * inv_eps;
        h.x = (hl[j0]     + hpa - 0.5f * inv_eps * fmaf(pa.x, pa.x, pa.y * pa.y)) * LOG2E;
        h.y = (hl[j0 + 1] + hpb - 0.5f * inv_eps * fmaf(pb.x, pb.x, pb.y * pb.y)) * LOG2E;
        h.z = (hl[j2]     + hpc - 0.5f * inv_eps * fmaf(pc.x, pc.x, pc.y * pc.y)) * LOG2E;
        h.w = (hl[j2 + 1] + hpd - 0.5f * inv_eps * fmaf(pd.x, pd.x, pd.y * pd.y)) * LOG2E;
        hc4[i] = h;
    }
    __syncthreads();

    const int lane = threadIdx.x & 63;
    const int wv = threadIdx.x >> 6;        // 8 waves/block
    const int row0 = rowTile * 32 + wv * RPW;
    const int gidx0 = batch * NPTS + row0;
    const float2* rp2 = (const float2*)(rowPts + (size_t)batch * NPTS * 2) + row0;
    const float* Lp = Ls + side * NE + gidx0;

    const float sc = inv_eps * LOG2E;
    float rx[RPW], ry[RPW], mest[RPW], s[RPW];
    #pragma unroll
    for (int r = 0; r < RPW; r++) {
        float2 p = rp2[r];
        rx[r] = p.x * sc;
        ry[r] = p.y * sc;
        mest[r] = initPhase ? 0.0f : Lp[r] * mscale;
        s[r] = 0.0f;
    }

    // Fused pass: 4 columns per lane-iter (3 b128 reads), 8 iters.
    #pragma unroll 2
    for (int it = 0; it < 8; it++) {
        float4 v0 = xy4[(it << 7) + lane];
        float4 v1 = xy4[(it << 7) + 64 + lane];
        float4 h  = hc4[(it << 6) + lane];
        #pragma unroll
        for (int r = 0; r < RPW; r++) {
            float t0 = fmaf(rx[r], v0.x, fmaf(ry[r], v0.y, h.x)) - mest[r];
            float t1 = fmaf(rx[r], v0.z, fmaf(ry[r], v0.w, h.y)) - mest[r];
            float t2 = fmaf(rx[r], v1.x, fmaf(ry[r], v1.y, h.z)) - mest[r];
            float t3 = fmaf(rx[r], v1.z, fmaf(ry[r], v1.w, h.w)) - mest[r];
            s[r] += (FAST_EXP2(t0) + FAST_EXP2(t1)) + (FAST_EXP2(t2) + FAST_EXP2(t3));
        }
    }
    #pragma unroll
    for (int r = 0; r < RPW; r++) s[r] = wred_sum(s[r]);

    int bad = 0;
    if (lane == 63) {
        #pragma unroll
        for (int r = 0; r < RPW; r++)
            bad |= !(s[r] > 1e-30f && s[r] < 1e34f);
    }
    if (__any(bad)) {
        // Exact 2-pass redo (wave-local; no barrier needed).
        float mm[RPW];
        #pragma unroll
        for (int r = 0; r < RPW; r++) mm[r] = -3.4e38f;
        #pragma unroll 2
        for (int it = 0; it < 8; it++) {
            float4 v0 = xy4[(it << 7) + lane];
            float4 v1 = xy4[(it << 7) + 64 + lane];
            float4 h  = hc4[(it << 6) + lane];
            #pragma unroll
            for (int r = 0; r < RPW; r++) {
                float t0 = fmaf(rx[r], v0.x, fmaf(ry[r], v0.y, h.x)) - mest[r];
                float t1 = fmaf(rx[r], v0.z, fmaf(ry[r], v0.w, h.y)) - mest[r];
                float t2 = fmaf(rx[r], v1.x, fmaf(ry[r], v1.y, h.z)) - mest[r];
                float t3 = fmaf(rx[r], v1.z, fmaf(ry[r], v1.w, h.w)) - mest[r];
                mm[r] = fmaxf(mm[r], fmaxf(fmaxf(t0, t1), fmaxf(t2, t3)));
            }
        }
        #pragma unroll
        for (int r = 0; r < RPW; r++) {
            mm[r] = wred_max(mm[r]);
            mm[r] = __shfl(mm[r], 63);   // broadcast shifted max
            s[r] = 0.0f;
        }
        #pragma unroll 2
        for (int it = 0; it < 8; it++) {
            float4 v0 = xy4[(it << 7) + lane];
            float4 v1 = xy4[(it << 7) + 64 + lane];
            float4 h  = hc4[(it << 6) + lane];
            #pragma unroll
            for (int r = 0; r < RPW; r++) {
                float t0 = fmaf(rx[r], v0.x, fmaf(ry[r], v0.y, h.x)) - mest[r] - mm[r];
                float t1 = fmaf(rx[r], v0.z, fmaf(ry[r], v0.w, h.y)) - mest[r] - mm[r];
                float t2 = fmaf(rx[r], v1.x, fmaf(ry[r], v1.y, h.z)) - mest[r] - mm[r];
                float t3 = fmaf(rx[r], v1.z, fmaf(ry[r], v1.w, h.w)) - mest[r] - mm[r];
                s[r] += (FAST_EXP2(t0) + FAST_EXP2(t1)) + (FAST_EXP2(t2) + FAST_EXP2(t3));
            }
        }
        #pragma unroll
        for (int r = 0; r < RPW; r++) {
            s[r] = wred_sum(s[r]);
            mest[r] += mm[r];            // final L = mest + mm + log2(s)
        }
    }

    if (lane == 63) {
        #pragma unroll
        for (int r = 0; r < RPW; r++) {
            float2 p = rp2[r];
            float hr = -0.5f * sc * fmaf(p.x, p.x, p.y * p.y);
            float L = mest[r] + FAST_LOG2(s[r]);          // log2-domain LSE
            float sm = -eps * LN2 * (hr + L);             // softmin value
            outPot[gidx0 + r] = c_old * ownPrev[gidx0 + r] + c_new * sm;
            Ls[side * NE + gidx0 + r] = L;                // estimator for next phase
        }
    }
}

__global__ void log_precompute(const float* __restrict__ a, const float* __restrict__ b,
                               float* __restrict__ loga, float* __restrict__ logb, int n)
{
    int i = blockIdx.x * blockDim.x + threadIdx.x;
    if (i < n) {
        loga[i] = logf(a[i]);
        logb[i] = logf(b[i]);
    }
}

__global__ __launch_bounds__(1024) void loss_reduce(
    const float* __restrict__ a, const float* __restrict__ bw,
    const float* __restrict__ f, const float* __restrict__ g,
    float* __restrict__ out)
{
    const float4* a4 = (const float4*)a;
    const float4* b4 = (const float4*)bw;
    const float4* f4 = (const float4*)f;
    const float4* g4 = (const float4*)g;
    float acc = 0.0f;
    for (int i = threadIdx.x; i < NE / 4; i += 1024) {
        float4 av = a4[i], fv = f4[i], bv = b4[i], gv = g4[i];
        acc += av.x * fv.x + av.y * fv.y + av.z * fv.z + av.w * fv.w;
        acc += bv.x * gv.x + bv.y * gv.y + bv.z * gv.z + bv.w * gv.w;
    }
    acc += __shfl_xor(acc, 32);
    acc += __shfl_xor(acc, 16);
    acc += __shfl_xor(acc, 8);
    acc += __shfl_xor(acc, 4);
    acc += __shfl_xor(acc, 2);
    acc += __shfl_xor(acc, 1);
    __shared__ float wsum[16];
    int wid = threadIdx.x >> 6;
    if ((threadIdx.x & 63) == 0) wsum[wid] = acc;
    __syncthreads();
    if (threadIdx.x < 16) {
        float v = wsum[threadIdx.x];
        v += __shfl_xor(v, 8, 16);
        v += __shfl_xor(v, 4, 16);
        v += __shfl_xor(v, 2, 16);
        v += __shfl_xor(v, 1, 16);
        if (threadIdx.x == 0) out[0] = v * (1.0f / NB);
    }
}

extern "C" void kernel_launch(void* const* d_in, const int* in_sizes, int n_in,
                              void* d_out, int out_size, void* d_ws, size_t ws_size,
                              hipStream_t stream)
{
    const float* a = (const float*)d_in[0];
    const float* x = (const float*)d_in[1];
    const float* b = (const float*)d_in[2];
    const float* y = (const float*)d_in[3];
    float* out = (float*)d_out;

    float* ws = (float*)d_ws;
    float* loga = ws + 0 * NE;
    float* logb = ws + 1 * NE;
    float* fA   = ws + 2 * NE;
    float* gA   = ws + 3 * NE;
    float* fB   = ws + 4 * NE;
    float* gB   = ws + 5 * NE;
    float* Ls   = ws + 6 * NE;      // 2*NE floats

    // eps annealing schedule (host-side, as in reference)
    double eps_list[32];
    int ne = 0;
    const double eps_final = 0.05 * 0.05;   // blur^p
    double eps = 2.0 * 2.0;                  // diameter^p
    while (eps > eps_final) { eps_list[ne++] = eps; eps *= 0.64; }  // scaling^p
    eps_list[ne++] = eps_final;              // ne == 18

    log_precompute<<<(NE + 255) / 256, 256, 0, stream>>>(a, b, loga, logb, NE);

    const float* fp = fA; const float* gp = gA;
    float* fn = fB; float* gn = gB;

    auto phase = [&](double e, double e_prev, float c_old, float c_new, int init) {
        sinkhorn_phase<<<1024, THREADS, 0, stream>>>(
            x, y, loga, logb, fp, gp, fn, gn, Ls,
            (float)e, (float)(1.0 / e), c_old, c_new,
            (float)(e_prev / e), init);
    };
    auto swapbuf = [&]() {
        const float* tf = fp; const float* tg = gp;
        fp = fn; gp = gn;
        fn = (float*)tf; gn = (float*)tg;
    };

    // init at eps0: h = log_b only; un-stabilized exponents are O(1) so
    // mest = 0 is in-band (band check still guards correctness).
    phase(eps_list[0], eps_list[0], 0.0f, 1.0f, 1);
    swapbuf();
    // annealed damped iterations
    double e_prev = eps_list[0];
    for (int k = 0; k < ne; k++) {
        phase(eps_list[k], e_prev, 0.5f, 0.5f, 0);
        e_prev = eps_list[k];
        swapbuf();
    }
    // final extrapolation at eps_final (no damping)
    phase(eps_list[ne - 1], e_prev, 0.0f, 1.0f, 0);
    // result potentials are in fn, gn

    loss_reduce<<<1, 1024, 0, stream>>>(a, b, fn, gn, out);
}

// Round 9
// 299.583 us; speedup vs baseline: 1.2578x; 1.1871x over previous
//
#include <hip/hip_runtime.h>
#include <cmath>

#define NB 8
#define NPTS 2048
#define NE (NB * NPTS)
#define THREADS 512
#define RPW 4   // rows per wave (2 packed pairs) -> 32 rows/block, 1024 blocks

typedef float v2f __attribute__((ext_vector_type(2)));

#if defined(__has_builtin)
#if __has_builtin(__builtin_amdgcn_exp2f)
#define FAST_EXP2(x) __builtin_amdgcn_exp2f(x)
#else
#define FAST_EXP2(x) exp2f(x)
#endif
#if __has_builtin(__builtin_amdgcn_logf)
#define FAST_LOG2(x) __builtin_amdgcn_logf(x)
#else
#define FAST_LOG2(x) log2f(x)
#endif
#else
#define FAST_EXP2(x) exp2f(x)
#define FAST_LOG2(x) log2f(x)
#endif

// ---- DPP wave64 reductions (VALU pipe only; result valid at lane 63) ----
template<int CTRL>
__device__ __forceinline__ float dpp_f(float v) {
    return __int_as_float(__builtin_amdgcn_update_dpp(
        __float_as_int(v), __float_as_int(v), CTRL, 0xF, 0xF, false));
}
__device__ __forceinline__ float wred_max(float v) {
    v = fmaxf(v, dpp_f<0xB1>(v));
    v = fmaxf(v, dpp_f<0x4E>(v));
    v = fmaxf(v, dpp_f<0x141>(v));
    v = fmaxf(v, dpp_f<0x140>(v));
    v = fmaxf(v, dpp_f<0x142>(v));
    v = fmaxf(v, dpp_f<0x143>(v));
    return v;  // lane 63 correct
}
__device__ __forceinline__ float wred_sum(float v) {
    v += dpp_f<0xB1>(v);
    v += dpp_f<0x4E>(v);
    v += dpp_f<0x141>(v);
    v += dpp_f<0x140>(v);
    v += dpp_f<0x142>(v);
    v += dpp_f<0x143>(v);
    return v;  // lane 63 correct
}

// One Sinkhorn "phase": softmin_eps(C,h) for all rows of both sides, damped.
// LDS: xy4 = raw float4 copy of column points (2 cols / 16B read);
//      hc  = linear log2-domain column constant (2 cols / 8B read).
// Inner loop packs ROW PAIRS into v2f: per 2 cols x 2 rows =
//   1 pk_sub (h - mest prefold) + 2 pk_fma + 2 v_exp + 1 pk_add.
// Stabilizer m_est = prev LSE * eps-ratio; band-validated (s in
// (1e-30,1e34) => full fp32 precision), exact wave-local 2-pass redo else.
__global__ __launch_bounds__(THREADS, 8) void sinkhorn_phase(
    const float* __restrict__ x, const float* __restrict__ y,
    const float* __restrict__ loga, const float* __restrict__ logb,
    const float* __restrict__ f_prev, const float* __restrict__ g_prev,
    float* __restrict__ f_next, float* __restrict__ g_next,
    float* __restrict__ Ls,          // [2][NB][NPTS] log2-domain LSE store
    float eps, float inv_eps, float c_old, float c_new,
    float mscale, int initPhase)
{
    __shared__ float4 xy4[NPTS / 2];   // 16 KB: {x_2k, y_2k, x_2k+1, y_2k+1}
    __shared__ float2 hc2[NPTS / 2];   // 8 KB: {hc_2k, hc_2k+1}

    const int blk = blockIdx.x;
    const int side = blk >> 9;          // 512 blocks/side
    const int rblk = blk & 511;
    const int batch = rblk >> 6;        // 64 row-tiles (32 rows) per batch
    const int rowTile = rblk & 63;

    const float* rowPts; const float* colPts; const float* hlog;
    const float* hpot; const float* ownPrev; float* outPot;
    if (side == 0) { rowPts=x; colPts=y; hlog=logb; hpot=g_prev; ownPrev=f_prev; outPot=f_next; }
    else           { rowPts=y; colPts=x; hlog=loga; hpot=f_prev; ownPrev=g_prev; outPot=g_next; }

    const float LOG2E = 1.4426950408889634f;
    const float LN2 = 0.69314718055994531f;

    // Stage xy: pure float4 copy (coalesced, no math).
    const float4* cp4 = ((const float4*)colPts) + (size_t)batch * (NPTS / 2);
    xy4[threadIdx.x]       = cp4[threadIdx.x];
    xy4[threadIdx.x + 512] = cp4[threadIdx.x + 512];

    // Stage hc linearly (same pattern as R6; scalar writes, conflict-free).
    {
        const float2* cp2 = (const float2*)(colPts + (size_t)batch * NPTS * 2);
        const float* hl = hlog + (size_t)batch * NPTS;
        const float* pp = hpot + (size_t)batch * NPTS;
        float* hcs = (float*)hc2;
        #pragma unroll
        for (int k = 0; k < NPTS / THREADS; k++) {
            int j = threadIdx.x + k * THREADS;
            float2 p = cp2[j];
            float hp = initPhase ? 0.0f : pp[j] * inv_eps;
            hcs[j] = (hl[j] + hp - 0.5f * inv_eps * fmaf(p.x, p.x, p.y * p.y)) * LOG2E;
        }
    }
    __syncthreads();

    const int lane = threadIdx.x & 63;
    const int wv = threadIdx.x >> 6;        // 8 waves/block
    const int row0 = rowTile * 32 + wv * RPW;
    const int gidx0 = batch * NPTS + row0;
    const float2* rp2 = (const float2*)(rowPts + (size_t)batch * NPTS * 2) + row0;
    const float* Lp = Ls + side * NE + gidx0;

    const float sc = inv_eps * LOG2E;
    v2f rxp[2], ryp[2], mestp[2], sp[2];
    #pragma unroll
    for (int p = 0; p < 2; p++) {
        float2 p0 = rp2[2 * p];
        float2 p1 = rp2[2 * p + 1];
        rxp[p] = (v2f){p0.x * sc, p1.x * sc};
        ryp[p] = (v2f){p0.y * sc, p1.y * sc};
        float m0 = initPhase ? 0.0f : Lp[2 * p] * mscale;
        float m1 = initPhase ? 0.0f : Lp[2 * p + 1] * mscale;
        mestp[p] = (v2f){m0, m1};
        sp[p] = (v2f){0.0f, 0.0f};
    }

    // Fused pass: 16 iters x 2 cols; per iter 1 ds_read_b128 + 1 ds_read_b64.
    #pragma unroll 4
    for (int it = 0; it < NPTS / 128; it++) {
        float4 v = xy4[(it << 6) + lane];
        float2 h = hc2[(it << 6) + lane];
        #pragma unroll
        for (int p = 0; p < 2; p++) {
            v2f h0 = (v2f){h.x, h.x} - mestp[p];
            v2f h1 = (v2f){h.y, h.y} - mestp[p];
            v2f t0 = __builtin_elementwise_fma(rxp[p], (v2f){v.x, v.x},
                        __builtin_elementwise_fma(ryp[p], (v2f){v.y, v.y}, h0));
            v2f t1 = __builtin_elementwise_fma(rxp[p], (v2f){v.z, v.z},
                        __builtin_elementwise_fma(ryp[p], (v2f){v.w, v.w}, h1));
            sp[p] += (v2f){FAST_EXP2(t0.x), FAST_EXP2(t0.y)};
            sp[p] += (v2f){FAST_EXP2(t1.x), FAST_EXP2(t1.y)};
        }
    }
    float s[RPW];
    s[0] = wred_sum(sp[0].x); s[1] = wred_sum(sp[0].y);
    s[2] = wred_sum(sp[1].x); s[3] = wred_sum(sp[1].y);

    int bad = 0;
    if (lane == 63) {
        #pragma unroll
        for (int r = 0; r < RPW; r++)
            bad |= !(s[r] > 1e-30f && s[r] < 1e34f);
    }
    float mesc[RPW] = { mestp[0].x, mestp[0].y, mestp[1].x, mestp[1].y };

    if (__any(bad)) {
        // Exact 2-pass redo (wave-local; no barrier needed).
        v2f mm[2];
        mm[0] = (v2f){-3.4e38f, -3.4e38f};
        mm[1] = (v2f){-3.4e38f, -3.4e38f};
        #pragma unroll 4
        for (int it = 0; it < NPTS / 128; it++) {
            float4 v = xy4[(it << 6) + lane];
            float2 h = hc2[(it << 6) + lane];
            #pragma unroll
            for (int p = 0; p < 2; p++) {
                v2f h0 = (v2f){h.x, h.x} - mestp[p];
                v2f h1 = (v2f){h.y, h.y} - mestp[p];
                v2f t0 = __builtin_elementwise_fma(rxp[p], (v2f){v.x, v.x},
                            __builtin_elementwise_fma(ryp[p], (v2f){v.y, v.y}, h0));
                v2f t1 = __builtin_elementwise_fma(rxp[p], (v2f){v.z, v.z},
                            __builtin_elementwise_fma(ryp[p], (v2f){v.w, v.w}, h1));
                mm[p] = __builtin_elementwise_max(mm[p],
                            __builtin_elementwise_max(t0, t1));
            }
        }
        float mmsc[RPW] = { mm[0].x, mm[0].y, mm[1].x, mm[1].y };
        #pragma unroll
        for (int r = 0; r < RPW; r++) {
            mmsc[r] = wred_max(mmsc[r]);
            mmsc[r] = __shfl(mmsc[r], 63);   // broadcast shifted max
        }
        v2f mmb[2] = { (v2f){mmsc[0], mmsc[1]}, (v2f){mmsc[2], mmsc[3]} };
        sp[0] = (v2f){0.0f, 0.0f};
        sp[1] = (v2f){0.0f, 0.0f};
        #pragma unroll 4
        for (int it = 0; it < NPTS / 128; it++) {
            float4 v = xy4[(it << 6) + lane];
            float2 h = hc2[(it << 6) + lane];
            #pragma unroll
            for (int p = 0; p < 2; p++) {
                v2f h0 = (v2f){h.x, h.x} - mestp[p] - mmb[p];
                v2f h1 = (v2f){h.y, h.y} - mestp[p] - mmb[p];
                v2f t0 = __builtin_elementwise_fma(rxp[p], (v2f){v.x, v.x},
                            __builtin_elementwise_fma(ryp[p], (v2f){v.y, v.y}, h0));
                v2f t1 = __builtin_elementwise_fma(rxp[p], (v2f){v.z, v.z},
                            __builtin_elementwise_fma(ryp[p], (v2f){v.w, v.w}, h1));
                sp[p] += (v2f){FAST_EXP2(t0.x), FAST_EXP2(t0.y)};
                sp[p] += (v2f){FAST_EXP2(t1.x), FAST_EXP2(t1.y)};
            }
        }
        s[0] = wred_sum(sp[0].x); s[1] = wred_sum(sp[0].y);
        s[2] = wred_sum(sp[1].x); s[3] = wred_sum(sp[1].y);
        #pragma unroll
        for (int r = 0; r < RPW; r++) mesc[r] += mmsc[r];
    }

    if (lane == 63) {
        #pragma unroll
        for (int r = 0; r < RPW; r++) {
            float2 p = rp2[r];
            float hr = -0.5f * sc * fmaf(p.x, p.x, p.y * p.y);
            float L = mesc[r] + FAST_LOG2(s[r]);          // log2-domain LSE
            float sm = -eps * LN2 * (hr + L);             // softmin value
            outPot[gidx0 + r] = c_old * ownPrev[gidx0 + r] + c_new * sm;
            Ls[side * NE + gidx0 + r] = L;                // estimator for next phase
        }
    }
}

__global__ void log_precompute(const float* __restrict__ a, const float* __restrict__ b,
                               float* __restrict__ loga, float* __restrict__ logb, int n)
{
    int i = blockIdx.x * blockDim.x + threadIdx.x;
    if (i < n) {
        loga[i] = logf(a[i]);
        logb[i] = logf(b[i]);
    }
}

__global__ __launch_bounds__(1024) void loss_reduce(
    const float* __restrict__ a, const float* __restrict__ bw,
    const float* __restrict__ f, const float* __restrict__ g,
    float* __restrict__ out)
{
    const float4* a4 = (const float4*)a;
    const float4* b4 = (const float4*)bw;
    const float4* f4 = (const float4*)f;
    const float4* g4 = (const float4*)g;
    float acc = 0.0f;
    for (int i = threadIdx.x; i < NE / 4; i += 1024) {
        float4 av = a4[i], fv = f4[i], bv = b4[i], gv = g4[i];
        acc += av.x * fv.x + av.y * fv.y + av.z * fv.z + av.w * fv.w;
        acc += bv.x * gv.x + bv.y * gv.y + bv.z * gv.z + bv.w * gv.w;
    }
    acc += __shfl_xor(acc, 32);
    acc += __shfl_xor(acc, 16);
    acc += __shfl_xor(acc, 8);
    acc += __shfl_xor(acc, 4);
    acc += __shfl_xor(acc, 2);
    acc += __shfl_xor(acc, 1);
    __shared__ float wsum[16];
    int wid = threadIdx.x >> 6;
    if ((threadIdx.x & 63) == 0) wsum[wid] = acc;
    __syncthreads();
    if (threadIdx.x < 16) {
        float v = wsum[threadIdx.x];
        v += __shfl_xor(v, 8, 16);
        v += __shfl_xor(v, 4, 16);
        v += __shfl_xor(v, 2, 16);
        v += __shfl_xor(v, 1, 16);
        if (threadIdx.x == 0) out[0] = v * (1.0f / NB);
    }
}

extern "C" void kernel_launch(void* const* d_in, const int* in_sizes, int n_in,
                              void* d_out, int out_size, void* d_ws, size_t ws_size,
                              hipStream_t stream)
{
    const float* a = (const float*)d_in[0];
    const float* x = (const float*)d_in[1];
    const float* b = (const float*)d_in[2];
    const float* y = (const float*)d_in[3];
    float* out = (float*)d_out;

    float* ws = (float*)d_ws;
    float* loga = ws + 0 * NE;
    float* logb = ws + 1 * NE;
    float* fA   = ws + 2 * NE;
    float* gA   = ws + 3 * NE;
    float* fB   = ws + 4 * NE;
    float* gB   = ws + 5 * NE;
    float* Ls   = ws + 6 * NE;      // 2*NE floats

    // eps annealing schedule (host-side, as in reference)
    double eps_list[32];
    int ne = 0;
    const double eps_final = 0.05 * 0.05;   // blur^p
    double eps = 2.0 * 2.0;                  // diameter^p
    while (eps > eps_final) { eps_list[ne++] = eps; eps *= 0.64; }  // scaling^p
    eps_list[ne++] = eps_final;              // ne == 18

    log_precompute<<<(NE + 255) / 256, 256, 0, stream>>>(a, b, loga, logb, NE);

    const float* fp = fA; const float* gp = gA;
    float* fn = fB; float* gn = gB;

    auto phase = [&](double e, double e_prev, float c_old, float c_new, int init) {
        sinkhorn_phase<<<1024, THREADS, 0, stream>>>(
            x, y, loga, logb, fp, gp, fn, gn, Ls,
            (float)e, (float)(1.0 / e), c_old, c_new,
            (float)(e_prev / e), init);
    };
    auto swapbuf = [&]() {
        const float* tf = fp; const float* tg = gp;
        fp = fn; gp = gn;
        fn = (float*)tf; gn = (float*)tg;
    };

    // init at eps0: h = log_b only; un-stabilized exponents are O(1) so
    // mest = 0 is in-band (band check still guards correctness).
    phase(eps_list[0], eps_list[0], 0.0f, 1.0f, 1);
    swapbuf();
    // annealed damped iterations
    double e_prev = eps_list[0];
    for (int k = 0; k < ne; k++) {
        phase(eps_list[k], e_prev, 0.5f, 0.5f, 0);
        e_prev = eps_list[k];
        swapbuf();
    }
    // final extrapolation at eps_final (no damping)
    phase(eps_list[ne - 1], e_prev, 0.0f, 1.0f, 0);
    // result potentials are in fn, gn

    loss_reduce<<<1, 1024, 0, stream>>>(a, b, fn, gn, out);
}